// Round 5
// baseline (4395.728 us; speedup 1.0000x reference)
//
#include <hip/hip_runtime.h>
#include <hip/hip_bf16.h>

// B=2048, D=256, H=266 (pad N->272, K->288), S=50. All f32 I/O; bf16 MFMA inside.
// Round 5: persistent PLAIN kernel (grid=256, guaranteed co-resident via
// launch_bounds(256,2): capacity >= 2 blocks/CU = 512 slots) with a manual
// device-scope atomic grid barrier (8 replicated counters, monotonic gen).
// 3 barriers per step. No cooperative API (round 4's silent failure).

#define BATCH 2048
#define DD    256
#define HH    266
#define HP    272
#define SS    50
#define BN_EPS 1e-5f
#define SIG   0.3f
#define AS_STRIDE 296   // LDS A-tile row stride in bf16 elems
#define NB    256       // persistent grid size

// f32 workspace offsets
#define XC_OFF 0              // [2048][256]
#define Y1_OFF 524288         // [2048][272]
#define Y2_OFF 1081344        // [2048][272]
#define V_OFF  1638400        // [2048]
#define S1_OFF 1640448        // 2 parity x 8 reps x 544
#define S2_OFF 1649152        // 2 parity x 8 reps x 544
#define S1V_OFF 1657856       // 8 x 544
#define S2V_OFF 1662208       // 8 x 544
#define SV_OFF  1666560       // 64
#define PR_OFF  1666624       // [2048][4] row partials (sx,sg,sgn,-)
#define BAR_OFF 1674816       // 8 counters x 16-uint stride (128 uints)
#define WQ_OFF  1674944       // bf16 region
#define ZERO_CNT 34496        // floats zeroed from S1_OFF (covers through BAR)

// swizzled weight strides (ushort units)
#define W1S 69632   // 8kt*17nt*512
#define W2S 78336   // 9*17*512
#define W3S 73728   // 9*16*512
#define W1Q_OFF 0
#define W2Q_OFF 3481600
#define W3Q_OFF 7398400
#define WV1Q_OFF 11084800
#define WV2Q_OFF 11154432

typedef unsigned short ushort_t;
using short8 = __attribute__((ext_vector_type(8))) short;
using f32x4  = __attribute__((ext_vector_type(4))) float;

__device__ __forceinline__ ushort_t f2b(float f) {   // f32 -> bf16 bits, RNE
    unsigned u = __float_as_uint(f);
    unsigned r = u + 0x7FFF + ((u >> 16) & 1);
    return (ushort_t)(r >> 16);
}
__device__ __forceinline__ unsigned pack2(float a, float b) {
    return (unsigned)f2b(a) | ((unsigned)f2b(b) << 16);
}

// ---------------- manual grid barrier ----------------
// 8 counters spaced 64B; each block arrives on counter (b&7); target 32/counter.
__device__ __forceinline__ void gbar(unsigned* __restrict__ bar, unsigned gen) {
    __syncthreads();
    if (threadIdx.x == 0) {
        __threadfence();   // release: flush this block's global writes
        atomicAdd(&bar[(blockIdx.x & 7) * 16], 1u);
        const unsigned tgt = gen * 32u;
        for (int i = 0; i < 8; ++i) {
            while (__hip_atomic_load(&bar[i * 16], __ATOMIC_RELAXED,
                                     __HIP_MEMORY_SCOPE_AGENT) < tgt)
                __builtin_amdgcn_s_sleep(1);
        }
        __threadfence();   // acquire: invalidate stale cached lines
    }
    __syncthreads();
}

// ---------------- init: xc = x, zero stat/PR/barrier buffers ----------------
__global__ __launch_bounds__(256) void k_init(const float* __restrict__ x,
                                              float* __restrict__ ws) {
    int idx = blockIdx.x * 256 + threadIdx.x;
    if (idx < BATCH * DD) {
        ws[XC_OFF + idx] = x[idx];
    } else {
        int z = idx - BATCH * DD;
        if (z < ZERO_CNT) ws[S1_OFF + z] = 0.0f;
    }
}

// ---------------- weight swizzle: f32 [K][N] -> bf16 B-frag layout ----------------
__global__ __launch_bounds__(256) void k_conv(const float* __restrict__ src,
                                              ushort_t* __restrict__ dst,
                                              int K, int N, int KT, int NT,
                                              long total) {
    long t = (long)blockIdx.x * 256 + threadIdx.x;
    if (t >= total) return;
    int per = KT * NT * 512;
    int step = (int)(t / per);
    int e = (int)(t - (long)step * per);
    int kt = e / (NT * 512);
    int r = e - kt * NT * 512;
    int nt = r / 512;
    int r2 = r & 511;
    int lane = r2 >> 3;
    int j = r2 & 7;
    int k = kt * 32 + (lane >> 4) * 8 + j;
    int n = nt * 16 + (lane & 15);
    float v = (k < K && n < N) ? src[(size_t)step * K * N + (size_t)k * N + n] : 0.f;
    dst[t] = f2b(v);
}

// BN affine constants: A = relu(a*y + c)
__device__ __forceinline__ void compute_ac(const float* __restrict__ stats_in,
                                           const float* __restrict__ g,
                                           const float* __restrict__ be,
                                           float (*AC)[HP]) {
    for (int t = threadIdx.x; t < HP; t += 256) {
        float a = 0.f, c = 0.f;
        if (t < HH) {
            float s = 0.f, q = 0.f;
            #pragma unroll
            for (int r = 0; r < 8; ++r) {
                s += stats_in[r * 544 + t];
                q += stats_in[r * 544 + 272 + t];
            }
            float mu  = s * (1.0f / 2048.0f);
            float var = q * (1.0f / 2048.0f) - mu * mu;
            float rs  = rsqrtf(fmaxf(var, 0.0f) + BN_EPS);
            a = g[t] * rs;
            c = be[t] - mu * a;
        }
        AC[0][t] = a;
        AC[1][t] = c;
    }
}

// stage raw f32 K=256 slab (16 rows) into bf16 LDS
__device__ __forceinline__ void stage_raw(ushort_t* As, const float* __restrict__ src) {
    const int tid = threadIdx.x;
    #pragma unroll
    for (int i = 0; i < 8; ++i) {
        int idx = tid + i * 256;
        int m = idx >> 7, d = idx & 127, kk = d * 2;
        ((unsigned*)As)[m * (AS_STRIDE/2) + d] =
            pack2(src[(size_t)m * DD + kk], src[(size_t)m * DD + kk + 1]);
    }
}

// stage affine-relu(Y) K=266->288 slab into bf16 LDS
__device__ __forceinline__ void stage_affine(ushort_t* As, const float* __restrict__ src,
                                             float (*AC)[HP]) {
    const int tid = threadIdx.x;
    #pragma unroll
    for (int i = 0; i < 9; ++i) {
        int idx = tid + i * 256;
        if (idx < 16 * 144) {
            int m = idx / 144, d = idx - m * 144, kk = d * 2;
            float v0 = (kk < HH)   ? fmaxf(fmaf(AC[0][kk],   src[(size_t)m*HP + kk],   AC[1][kk]),   0.f) : 0.f;
            float v1 = (kk+1 < HH) ? fmaxf(fmaf(AC[0][kk+1], src[(size_t)m*HP + kk+1], AC[1][kk+1]), 0.f) : 0.f;
            ((unsigned*)As)[m * (AS_STRIDE/2) + d] = pack2(v0, v1);
        }
    }
}

// NT=17 GEMM, N-split: wave wv handles tiles start+wv+4i (i<3) while < start+cnt
__device__ __forceinline__ void gemm_nt17(const ushort_t* As, int KT, int start, int cnt,
                                          const ushort_t* __restrict__ Wq,
                                          const float* __restrict__ bias,
                                          float* __restrict__ yout, int row0,
                                          float* __restrict__ statrep,
                                          int lane, int wv) {
    const int quad = lane >> 4, l15 = lane & 15;
    f32x4 acc[3];
    #pragma unroll
    for (int i = 0; i < 3; ++i) acc[i] = (f32x4){0.f,0.f,0.f,0.f};
    for (int kt = 0; kt < KT; ++kt) {
        short8 af = *(const short8*)&As[l15 * AS_STRIDE + kt * 32 + quad * 8];
        const ushort_t* wp = Wq + ((size_t)(kt * 17 + start + wv)) * 512 + lane * 8;
        #pragma unroll
        for (int i = 0; i < 3; ++i) {
            if (wv + 4*i < cnt) {
                short8 bf = *(const short8*)(wp + (size_t)i * 2048);
                acc[i] = __builtin_amdgcn_mfma_f32_16x16x32_bf16(af, bf, acc[i], 0, 0, 0);
            }
        }
    }
    #pragma unroll
    for (int i = 0; i < 3; ++i) {
        if (wv + 4*i >= cnt) continue;
        int col = (start + wv + 4*i) * 16 + l15;
        float bj = (col < HH) ? bias[col] : 0.f;
        float y0 = acc[i][0]+bj, y1 = acc[i][1]+bj, y2 = acc[i][2]+bj, y3 = acc[i][3]+bj;
        yout[(size_t)(row0 + quad*4 + 0) * HP + col] = y0;
        yout[(size_t)(row0 + quad*4 + 1) * HP + col] = y1;
        yout[(size_t)(row0 + quad*4 + 2) * HP + col] = y2;
        yout[(size_t)(row0 + quad*4 + 3) * HP + col] = y3;
        float sp = y0+y1+y2+y3;
        float sq = y0*y0+y1*y1+y2*y2+y3*y3;
        sp += __shfl_xor(sp, 16); sp += __shfl_xor(sp, 32);
        sq += __shfl_xor(sq, 16); sq += __shfl_xor(sq, 32);
        if (quad == 0 && col < HH) {
            atomicAdd(statrep + col, sp);
            atomicAdd(statrep + 272 + col, sq);
        }
    }
}

// ---------------- persistent scan kernel (plain launch, 256 blocks) ----------------
struct PParams {
    float* xc; float* Y1; float* Y2; float* V; float* S1; float* S2; float* PR; float* out;
    unsigned* bar;
    const float* g1; const float* be1; const float* g2; const float* be2;
    const float* b1; const float* b2; const float* b3; const float* law;
    const float* dW; const float* tg;
    const ushort_t* W1q; const ushort_t* W2q; const ushort_t* W3q;
};

__global__ __launch_bounds__(256, 2) void k_persist(PParams P) {
    __shared__ ushort_t As[16 * AS_STRIDE];
    __shared__ float AC[2][HP];
    const int tid  = threadIdx.x;
    const int lane = tid & 63;
    const int wv   = tid >> 6;
    const int quad = lane >> 4;
    const int l15  = lane & 15;
    const int b    = blockIdx.x;
    const int slab = b >> 1;          // 0..127
    const int half = b & 1;           // N-half
    const int row0 = slab * 16;
    const int start17 = half ? 9 : 0;
    const int cnt17   = half ? 8 : 9;
    const int srep = (slab & 7) * 544;
    unsigned gen = 0;

    for (int s = 0; s < SS; ++s) {
        const int p = s & 1;
        const float h   = P.tg[s + 1] - P.tg[s];
        const float srt = SIG * sqrtf(h);

        // ---- phase A: P2(s) = relu(bn1(Y1)) @ W2 + b2 -> Y2, stats2[p] ----
        compute_ac(P.S1 + p * 4352, P.g1 + s * HH, P.be1 + s * HH, AC);
        __syncthreads();
        stage_affine(As, P.Y1 + (size_t)row0 * HP, AC);
        __syncthreads();
        gemm_nt17(As, 9, start17, cnt17, P.W2q + (size_t)s * W2S, P.b2 + s * HH,
                  P.Y2, row0, P.S2 + p * 4352 + srep, lane, wv);
        gbar(P.bar, ++gen);

        // ---- phase B: P3(s) = relu(bn2(Y2)) @ W3 + b3 -> grad; xc update; PR partials ----
        if (b < 17) P.S1[p * 4352 + b * 256 + tid] = 0.0f;   // re-zero consumed stats1
        compute_ac(P.S2 + p * 4352, P.g2 + s * HH, P.be2 + s * HH, AC);
        __syncthreads();
        stage_affine(As, P.Y2 + (size_t)row0 * HP, AC);
        __syncthreads();
        {
            const int t0 = half * 8 + wv;     // tiles t0 and t0+4 (NT=16)
            f32x4 acc0 = {0.f,0.f,0.f,0.f}, acc1 = {0.f,0.f,0.f,0.f};
            const ushort_t* w3 = P.W3q + (size_t)s * W3S;
            for (int kt = 0; kt < 9; ++kt) {
                short8 af = *(const short8*)&As[l15 * AS_STRIDE + kt * 32 + quad * 8];
                const ushort_t* wp = w3 + ((size_t)(kt * 16 + t0)) * 512 + lane * 8;
                acc0 = __builtin_amdgcn_mfma_f32_16x16x32_bf16(af, *(const short8*)wp,          acc0, 0, 0, 0);
                acc1 = __builtin_amdgcn_mfma_f32_16x16x32_bf16(af, *(const short8*)(wp + 2048), acc1, 0, 0, 0);
            }
            const float* dwp = P.dW + (size_t)s * BATCH * DD;
            float gr[2][4], xv[2][4], dv[2][4];
            float sxr[4] = {0,0,0,0}, sgr[4] = {0,0,0,0}, sgnr[4] = {0,0,0,0};
            #pragma unroll
            for (int i = 0; i < 2; ++i) {
                const f32x4 a = i ? acc1 : acc0;
                const int col = (t0 + 4*i) * 16 + l15;
                const float bb = P.b3[s * DD + col];
                const float lw = P.law[s * DD + col];
                #pragma unroll
                for (int r = 0; r < 4; ++r) {
                    int row = row0 + quad * 4 + r;
                    float g = a[r] + bb;
                    float x = P.xc[(size_t)row * DD + col];
                    float d = dwp[(size_t)row * DD + col];
                    gr[i][r] = g; xv[i][r] = x; dv[i][r] = d;
                    float dd = x - lw;
                    sxr[r]  = fmaf(dd, dd, sxr[r]);
                    sgr[r]  = fmaf(g, g, sgr[r]);
                    sgnr[r] = fmaf(g, d, sgnr[r]);
                }
            }
            #pragma unroll
            for (int off = 1; off < 16; off <<= 1) {
                #pragma unroll
                for (int r = 0; r < 4; ++r) {
                    sxr[r]  += __shfl_xor(sxr[r],  off);
                    sgr[r]  += __shfl_xor(sgr[r],  off);
                    sgnr[r] += __shfl_xor(sgnr[r], off);
                }
            }
            if (l15 == 0) {
                #pragma unroll
                for (int r = 0; r < 4; ++r) {
                    int row = row0 + quad * 4 + r;
                    atomicAdd(P.PR + row * 4 + 0, sxr[r]);
                    atomicAdd(P.PR + row * 4 + 1, sgr[r]);
                    atomicAdd(P.PR + row * 4 + 2, sgnr[r]);
                }
            }
            #pragma unroll
            for (int i = 0; i < 2; ++i) {
                const int col = (t0 + 4*i) * 16 + l15;
                #pragma unroll
                for (int r = 0; r < 4; ++r) {
                    int row = row0 + quad * 4 + r;
                    P.xc[(size_t)row * DD + col] = xv[i][r] - gr[i][r] * h + srt * dv[i][r];
                }
            }
        }
        gbar(P.bar, ++gen);

        // ---- phase C: v-update(s) + P1(s+1) = xc @ W1 + b1 -> Y1, stats1[1-p] ----
        if (b < 17) P.S2[p * 4352 + b * 256 + tid] = 0.0f;   // re-zero consumed stats2
        if (half == 0 && tid < 16) {
            int row = row0 + tid;
            float sx  = P.PR[row * 4 + 0];
            float sg  = P.PR[row * 4 + 1];
            float sgn = P.PR[row * 4 + 2];
            float f  = 0.5f * (sx + sg);       // KAPPA = 1
            float vn = P.V[row] - f * h + srt * sgn;
            P.V[row] = vn;
            P.PR[row * 4 + 0] = 0.f;
            P.PR[row * 4 + 1] = 0.f;
            P.PR[row * 4 + 2] = 0.f;
            if (s == SS - 1) P.out[row] = vn;
        }
        if (s < SS - 1) {
            stage_raw(As, P.xc + (size_t)row0 * DD);
            __syncthreads();
            gemm_nt17(As, 8, start17, cnt17, P.W1q + (size_t)(s + 1) * W1S,
                      P.b1 + (s + 1) * HH, P.Y1, row0,
                      P.S1 + ((s + 1) & 1) * 4352 + srep, lane, wv);
        }
        gbar(P.bar, ++gen);
    }
}

// ---------------- k_lin: regular-launch GEMM for v0 net + P1(0) ----------------
__global__ __launch_bounds__(256) void k_lin(
    int mode, int KT, const float* __restrict__ xsrc, int xld,
    const float* __restrict__ stats_in, const float* __restrict__ g,
    const float* __restrict__ be,
    const ushort_t* __restrict__ Wq, const float* __restrict__ bias,
    float* __restrict__ yout, float* __restrict__ stats_out)
{
    __shared__ ushort_t As[16 * AS_STRIDE];
    __shared__ float AC[2][HP];
    const int tid  = threadIdx.x;
    const int lane = tid & 63;
    const int wv   = tid >> 6;
    const int hhalf = blockIdx.x & 1;
    const int row0 = (blockIdx.x >> 1) * 16;

    if (mode == 2) {
        compute_ac(stats_in, g, be, AC);
        __syncthreads();
        stage_affine(As, xsrc + (size_t)row0 * HP, AC);
    } else {
        stage_raw(As, xsrc + (size_t)row0 * DD);
    }
    __syncthreads();

    gemm_nt17(As, KT, hhalf ? 9 : 0, hhalf ? 8 : 9, Wq, bias, yout, row0,
              stats_out + (blockIdx.x & 7) * 544, lane, wv);
}

// ---------------- v0 layer 3 (N=1) ----------------
__global__ __launch_bounds__(256) void k_v0l3(
    const float* __restrict__ y2, const float* __restrict__ stats_in,
    const float* __restrict__ gv, const float* __restrict__ bev,
    const float* __restrict__ wv3, const float* __restrict__ bv3,
    float* __restrict__ vout, float* __restrict__ sv)
{
    __shared__ float AC[2][HP];
    __shared__ float WC[HP];
    __shared__ float rv[16], rq[16];
    const int tid = threadIdx.x;

    compute_ac(stats_in, gv, bev, AC);
    for (int t = tid; t < HP; t += 256)
        WC[t] = (t < HH) ? wv3[t] : 0.0f;
    __syncthreads();

    const int r   = tid >> 4;
    const int ks  = tid & 15;
    const int row = blockIdx.x * 16 + r;
    const int k0  = ks * 17;
    const int k1  = (k0 + 17 < HH) ? (k0 + 17) : HH;
    float acc = 0.0f;
    for (int k = k0; k < k1; ++k) {
        float y  = y2[(size_t)row * HP + k];
        float a2 = fmaxf(fmaf(AC[0][k], y, AC[1][k]), 0.0f);
        acc = fmaf(a2, WC[k], acc);
    }
    acc += __shfl_xor(acc, 1);
    acc += __shfl_xor(acc, 2);
    acc += __shfl_xor(acc, 4);
    acc += __shfl_xor(acc, 8);
    if (ks == 0) {
        float y = acc + bv3[0];
        vout[row] = y;
        rv[r] = y;
        rq[r] = y * y;
    }
    __syncthreads();
    if (tid == 0) {
        float s = 0.f, q = 0.f;
        #pragma unroll
        for (int i = 0; i < 16; ++i) { s += rv[i]; q += rq[i]; }
        atomicAdd(sv, s);
        atomicAdd(sv + 1, q);
    }
}

__global__ __launch_bounds__(256) void k_v0fin(
    float* __restrict__ v, const float* __restrict__ sv,
    const float* __restrict__ gv3, const float* __restrict__ bev3)
{
    int row = blockIdx.x * 256 + threadIdx.x;
    float mu  = sv[0] * (1.0f / 2048.0f);
    float var = sv[1] * (1.0f / 2048.0f) - mu * mu;
    float rs  = rsqrtf(fmaxf(var, 0.0f) + BN_EPS);
    float y   = v[row];
    v[row] = fmaxf(gv3[0] * (y - mu) * rs + bev3[0], 0.0f);
}

extern "C" void kernel_launch(void* const* d_in, const int* in_sizes, int n_in,
                              void* d_out, int out_size, void* d_ws, size_t ws_size,
                              hipStream_t stream)
{
    (void)in_sizes; (void)n_in; (void)out_size; (void)ws_size;
    const float* x    = (const float*)d_in[0];
    const float* dW   = (const float*)d_in[1];
    const float* law  = (const float*)d_in[2];
    const float* tg   = (const float*)d_in[3];
    const float* W1   = (const float*)d_in[4];
    const float* b1   = (const float*)d_in[5];
    const float* g1   = (const float*)d_in[6];
    const float* be1  = (const float*)d_in[7];
    const float* W2   = (const float*)d_in[8];
    const float* b2   = (const float*)d_in[9];
    const float* g2   = (const float*)d_in[10];
    const float* be2  = (const float*)d_in[11];
    const float* W3   = (const float*)d_in[12];
    const float* b3   = (const float*)d_in[13];
    const float* Wv1  = (const float*)d_in[14];
    const float* bv1  = (const float*)d_in[15];
    const float* gv1  = (const float*)d_in[16];
    const float* bev1 = (const float*)d_in[17];
    const float* Wv2  = (const float*)d_in[18];
    const float* bv2  = (const float*)d_in[19];
    const float* gv2  = (const float*)d_in[20];
    const float* bev2 = (const float*)d_in[21];
    const float* Wv3  = (const float*)d_in[22];
    const float* bv3  = (const float*)d_in[23];
    const float* gv3  = (const float*)d_in[24];
    const float* bev3 = (const float*)d_in[25];

    float* ws = (float*)d_ws;
    float* xc  = ws + XC_OFF;
    float* Y1  = ws + Y1_OFF;
    float* Y2  = ws + Y2_OFF;
    float* V   = ws + V_OFF;
    float* S1  = ws + S1_OFF;
    float* S2  = ws + S2_OFF;
    float* S1v = ws + S1V_OFF;
    float* S2v = ws + S2V_OFF;
    float* SV  = ws + SV_OFF;
    float* PR  = ws + PR_OFF;
    unsigned* BAR = (unsigned*)(ws + BAR_OFF);
    ushort_t* WQ = (ushort_t*)(ws + WQ_OFF);
    ushort_t* W1q  = WQ + W1Q_OFF;
    ushort_t* W2q  = WQ + W2Q_OFF;
    ushort_t* W3q  = WQ + W3Q_OFF;
    ushort_t* Wv1q = WQ + WV1Q_OFF;
    ushort_t* Wv2q = WQ + WV2Q_OFF;
    float* out = (float*)d_out;

    k_init<<<2183, 256, 0, stream>>>(x, ws);
    k_conv<<<13600, 256, 0, stream>>>(W1,  W1q,  DD, HH, 8, 17, (long)SS * W1S);
    k_conv<<<15300, 256, 0, stream>>>(W2,  W2q,  HH, HH, 9, 17, (long)SS * W2S);
    k_conv<<<14400, 256, 0, stream>>>(W3,  W3q,  HH, DD, 9, 16, (long)SS * W3S);
    k_conv<<<272,   256, 0, stream>>>(Wv1, Wv1q, DD, HH, 8, 17, (long)W1S);
    k_conv<<<306,   256, 0, stream>>>(Wv2, Wv2q, HH, HH, 9, 17, (long)W2S);

    // v0 network (regular launches)
    k_lin<<<256, 256, 0, stream>>>(0, 8, x, DD, nullptr, nullptr, nullptr,
                                   Wv1q, bv1, Y1, S1v);
    k_lin<<<256, 256, 0, stream>>>(2, 9, Y1, HP, S1v, gv1, bev1,
                                   Wv2q, bv2, Y2, S2v);
    k_v0l3<<<128, 256, 0, stream>>>(Y2, S2v, gv2, bev2, Wv3, bv3, V, SV);
    k_v0fin<<<8, 256, 0, stream>>>(V, SV, gv3, bev3);

    // P1(0): xc == x, stats1 parity 0
    k_lin<<<256, 256, 0, stream>>>(0, 8, x, DD, nullptr, nullptr, nullptr,
                                   W1q, b1, Y1, S1);

    // persistent scan: 50 steps, 3 manual grid barriers each
    PParams pp;
    pp.xc = xc; pp.Y1 = Y1; pp.Y2 = Y2; pp.V = V;
    pp.S1 = S1; pp.S2 = S2; pp.PR = PR; pp.out = out; pp.bar = BAR;
    pp.g1 = g1; pp.be1 = be1; pp.g2 = g2; pp.be2 = be2;
    pp.b1 = b1; pp.b2 = b2; pp.b3 = b3; pp.law = law;
    pp.dW = dW; pp.tg = tg;
    pp.W1q = W1q; pp.W2q = W2q; pp.W3q = W3q;
    k_persist<<<NB, 256, 0, stream>>>(pp);
}